// Round 5
// baseline (535.309 us; speedup 1.0000x reference)
//
#include <hip/hip_runtime.h>
#include <hip/hip_bf16.h>
#include <cstdint>
#include <cstddef>
#include <type_traits>

typedef _Float16 half8 __attribute__((ext_vector_type(8)));
typedef _Float16 half4v __attribute__((ext_vector_type(4)));
typedef float float4v __attribute__((ext_vector_type(4)));

// ---------------- CSR build ----------------

__global__ void k_zero_int(int* __restrict__ p, int n) {
  int i = blockIdx.x * blockDim.x + threadIdx.x;
  if (i < n) p[i] = 0;
}

__global__ void k_count(const int* __restrict__ dst, int* __restrict__ cnt, int E) {
  int e = blockIdx.x * blockDim.x + threadIdx.x;
  if (e < E) atomicAdd(&cnt[dst[e]], 1);
}

// hierarchical exclusive scan: local (per-1024 block) -> sums -> fixup
__global__ __launch_bounds__(1024) void k_scan_local(const int* __restrict__ cnt,
                                                     int* __restrict__ rowp,
                                                     int* __restrict__ bsum, int n) {
  __shared__ int sm[1024];
  int tid = threadIdx.x;
  int i = blockIdx.x * 1024 + tid;
  int v = (i < n) ? cnt[i] : 0;
  sm[tid] = v;
  __syncthreads();
  for (int off = 1; off < 1024; off <<= 1) {
    int t = (tid >= off) ? sm[tid - off] : 0;
    __syncthreads();
    sm[tid] += t;
    __syncthreads();
  }
  if (i < n) rowp[i] = sm[tid] - v;  // exclusive (pre-fixup)
  if (tid == 1023) bsum[blockIdx.x] = sm[1023];
}

__global__ __launch_bounds__(1024) void k_scan_sums(int* __restrict__ bsum, int nb) {
  __shared__ int sm[1024];
  int tid = threadIdx.x;
  int v = (tid < nb) ? bsum[tid] : 0;
  sm[tid] = v;
  __syncthreads();
  for (int off = 1; off < 1024; off <<= 1) {
    int t = (tid >= off) ? sm[tid - off] : 0;
    __syncthreads();
    sm[tid] += t;
    __syncthreads();
  }
  if (tid < nb) bsum[tid] = sm[tid] - v;  // exclusive
}

// fixup + cursor copy + dinv, fused
__global__ void k_finalize(int* __restrict__ rowp, const int* __restrict__ bsum,
                           const int* __restrict__ cnt, int* __restrict__ cursor,
                           float* __restrict__ dinv, int n, int E) {
  int i = blockIdx.x * blockDim.x + threadIdx.x;
  if (i < n) {
    int v = rowp[i] + bsum[i >> 10];
    rowp[i] = v;
    cursor[i] = v;
    dinv[i] = rsqrtf((float)(cnt[i] + 1));  // +1 self loop
  }
  if (i == 0) rowp[n] = E;
}

__global__ void k_fill(const int* __restrict__ src, const int* __restrict__ dst,
                       int* __restrict__ cursor, int* __restrict__ csr_src, int E) {
  int e = blockIdx.x * blockDim.x + threadIdx.x;
  if (e < E) {
    int pos = atomicAdd(&cursor[dst[e]], 1);
    csr_src[pos] = src[e];
  }
}

// ---------------- fused weight convert+transpose (3 matrices in one launch) --------

__global__ void k_w_convert_all(const float* __restrict__ W1, const float* __restrict__ Wg1,
                                const float* __restrict__ Wg2, _Float16* __restrict__ W1t,
                                _Float16* __restrict__ Wg1t, _Float16* __restrict__ Wg2t,
                                int in_dim, int hid) {
  int idx = blockIdx.x * blockDim.x + threadIdx.x;
  int n1 = in_dim * hid;
  int n2 = hid * hid;
  if (idx < n1) {
    int n = idx / in_dim, k = idx - n * in_dim;
    W1t[idx] = (_Float16)W1[(size_t)k * hid + n];
  } else if (idx < n1 + n2) {
    int i2 = idx - n1;
    int n = i2 / hid, k = i2 - n * hid;
    Wg1t[i2] = (_Float16)Wg1[(size_t)k * hid + n];
  } else if (idx < n1 + 2 * n2) {
    int i2 = idx - n1 - n2;
    int n = i2 / hid, k = i2 - n * hid;
    Wg2t[i2] = (_Float16)Wg2[(size_t)k * hid + n];
  }
}

// ---------------- fp16 MFMA GEMM, 256x256 tile, counted-vmcnt 3-buffer pipeline ----
// Round-3 post-mortem: __syncthreads() per k-step compiles to s_waitcnt vmcnt(0)+
// s_barrier -> full DMA drain every k-step, 1 block/CU, zero overlap -> 92% idle.
// Fix (T3/T4, m218): raw s_barrier + COUNTED s_waitcnt vmcnt(IPT). 3 LDS buffers,
// DMA depth 2 (tiles kt+1, kt+2 in flight across the barrier; never drain to 0
// in the main loop). Per-tile DMA instructions per thread: IPT = 6 (fp32 A: 4 A +
// 2 B) or 4 (fp16 A: 2 A + 2 B). vmcnt(IPT) at top of iter kt => tile kt fully
// resident (only tile kt+1's IPT newest remain), then s_barrier publishes all
// waves' contributions.
// Safety: buffer for tile kt+2 was last read at tile kt-1, complete before the
// top-of-kt barrier (reads consumed by MFMAs in program order). In-loop VMEM is
// ONLY the staging DMA; the per-iteration asm "memory" clobbers fence epilogue
// loads out of the loop, keeping vmcnt counts exact. VMEM retires in order per
// wave, so the counts are exact.
// Data layout / DMA mapping byte-identical to the harness-verified round-3 code
// (fp32 A split into two 16-float half-buffers => 64B LDS rows, source
// pre-permuted, LDS dest linear).
// (Resubmit of round-4: bench infra failed twice; no counters were produced.
// Audit found no deadlock/fault path: uniform barriers, exact vmcnt counts,
// WAR-safe buffer rotation, in-bounds addresses, 144KB < 160KB LDS.)

__device__ __forceinline__ void gl_lds16(const void* g, void* l) {
  __builtin_amdgcn_global_load_lds(
      (const __attribute__((address_space(1))) void*)g,
      (__attribute__((address_space(3))) void*)l, 16, 0, 0);
}

#define VMCNT(n) asm volatile("s_waitcnt vmcnt(" #n ")" ::: "memory")

template <int RA>
__device__ __forceinline__ void dma_tile(const char* const (&aS)[RA], const int (&aD)[RA],
                                         const char* const (&bS)[2], const int (&bD)[2],
                                         char* ab, char* bb, size_t advA, size_t advB) {
#pragma unroll
  for (int rr = 0; rr < RA; ++rr) gl_lds16(aS[rr] + advA, ab + aD[rr]);
#pragma unroll
  for (int rr = 0; rr < 2; ++rr) gl_lds16(bS[rr] + advB, bb + bD[rr]);
}

template <typename AT, int RELU, int BIAS, int SCALE>
__global__ __launch_bounds__(512) void k_gemm_mfma(const AT* __restrict__ A,
                                                   const _Float16* __restrict__ Bt,
                                                   const float* __restrict__ bias,
                                                   const float* __restrict__ rowscale,
                                                   _Float16* __restrict__ out,
                                                   int M, int N, int K) {
  __shared__ alignas(16) AT Asm[3][256 * 32];
  __shared__ alignas(16) _Float16 Bsm[3][256 * 32];
  constexpr bool AF32 = std::is_same_v<AT, float>;
  constexpr int RA = AF32 ? 4 : 2;                   // A DMA rounds (8KB each)
  constexpr int ABUFB = 256 * 32 * (int)sizeof(AT);  // 32KB / 16KB
  constexpr int BBUFB = 256 * 32 * 2;                // 16KB

  const int tid = threadIdx.x;
  const int wv = tid >> 6;          // 0..7
  const int ln = tid & 63;
  const int quad = ln >> 4;
  const int l15 = ln & 15;
  const int wm = (wv >> 2) * 128;   // 0 or 128
  const int wn = (wv & 3) * 64;     // 0,64,128,192

  const int bm = (int)blockIdx.x * 256;

  // ---- per-thread DMA source precompute (dest linear; source pre-permuted) ----
  const char* aSrcB[RA];
  int aDstOff[RA];
#pragma unroll
  for (int rr = 0; rr < RA; ++rr) {
    int q = rr * 8192 + wv * 1024 + ln * 16;  // byte pos in A buf
    int row, colE;                            // colE in elements
    if constexpr (AF32) {
      int h = q >> 14;                        // half-buffer (cols 0-15 | 16-31)
      row = (q >> 6) & 255;
      colE = ((q & 63) >> 2) + (h << 4);
    } else {
      row = q >> 6;
      colE = (q & 63) >> 1;
    }
    int grow = bm + row; if (grow > M - 1) grow = M - 1;  // clamp; epilogue masks
    aSrcB[rr] = (const char*)(A + (size_t)grow * K + colE);
    aDstOff[rr] = rr * 8192 + wv * 1024;      // wave-uniform (lane*16 added by HW)
  }
  const char* bSrcB[2];
  int bDstOff[2];
#pragma unroll
  for (int rr = 0; rr < 2; ++rr) {
    int q = rr * 8192 + wv * 1024 + ln * 16;  // byte pos in B buf
    int row = q >> 6;
    int colH = (q & 63) >> 1;
    bSrcB[rr] = (const char*)(Bt + (size_t)row * K + colH);
    bDstOff[rr] = rr * 8192 + wv * 1024;
  }

  float4v acc[8][4];
#pragma unroll
  for (int i = 0; i < 8; ++i)
#pragma unroll
    for (int j = 0; j < 4; ++j) acc[i][j] = (float4v){0.f, 0.f, 0.f, 0.f};

  const int nk = K >> 5;   // >= 8 always here

  char* const Ab0 = (char*)&Asm[0][0];
  char* const Bb0 = (char*)&Bsm[0][0];

  // prologue: DMA tile 0 -> buf 0, tile 1 -> buf 1 (2*IPT outstanding)
  dma_tile<RA>(aSrcB, aDstOff, bSrcB, bDstOff, Ab0, Bb0, 0, 0);
  dma_tile<RA>(aSrcB, aDstOff, bSrcB, bDstOff, Ab0 + ABUFB, Bb0 + BBUFB,
               (size_t)32 * sizeof(AT), 64);

  int c0 = 0;  // buffer holding tile kt
  for (int kt = 0; kt < nk; ++kt) {
    // wait: tile kt resident (leave tile kt+1's IPT newest in flight)
    if (kt + 1 < nk) {
      if constexpr (AF32) { VMCNT(6); } else { VMCNT(4); }
    } else {
      VMCNT(0);
    }
    __builtin_amdgcn_sched_barrier(0);
    __builtin_amdgcn_s_barrier();       // publish all waves' tile-kt DMA
    __builtin_amdgcn_sched_barrier(0);

    // issue tile kt+2 DMA into the buffer last read at tile kt-1
    if (kt + 2 < nk) {
      int c2 = c0 + 2; if (c2 >= 3) c2 -= 3;
      dma_tile<RA>(aSrcB, aDstOff, bSrcB, bDstOff,
                   Ab0 + (size_t)c2 * ABUFB, Bb0 + (size_t)c2 * BBUFB,
                   (size_t)(kt + 2) * 32 * sizeof(AT), (size_t)(kt + 2) * 64);
      __builtin_amdgcn_sched_barrier(0);  // keep DMA issue ahead of ds_reads
    }

    // compute tile kt from buffer c0
    const AT* Ab = &Asm[c0][0];
    const _Float16* Bb = &Bsm[c0][0];
    half8 bf[4];
#pragma unroll
    for (int j = 0; j < 4; ++j)
      bf[j] = *(const half8*)(Bb + (wn + j * 16 + l15) * 32 + quad * 8);
#pragma unroll
    for (int i = 0; i < 8; ++i) {
      int rowa = wm + i * 16 + l15;
      half8 af;
      if constexpr (AF32) {
        // split-half: cols quad*8..quad*8+7 live in half (quad>>1), sub (quad&1)
        const float* ap = Ab + (quad >> 1) * 4096 + rowa * 16 + (quad & 1) * 8;
        float4v f0 = *(const float4v*)ap;
        float4v f1 = *(const float4v*)(ap + 4);
        af[0] = (_Float16)f0[0]; af[1] = (_Float16)f0[1];
        af[2] = (_Float16)f0[2]; af[3] = (_Float16)f0[3];
        af[4] = (_Float16)f1[0]; af[5] = (_Float16)f1[1];
        af[6] = (_Float16)f1[2]; af[7] = (_Float16)f1[3];
      } else {
        af = *(const half8*)(Ab + rowa * 32 + quad * 8);
      }
#pragma unroll
      for (int j = 0; j < 4; ++j)
        acc[i][j] = __builtin_amdgcn_mfma_f32_16x16x32_f16(af, bf[j], acc[i][j], 0, 0, 0);
    }

    c0 = (c0 == 2) ? 0 : c0 + 1;
  }

  // epilogue: C/D layout col=lane&15, row=quad*4+reg
#pragma unroll
  for (int j = 0; j < 4; ++j) {
    int c = wn + j * 16 + l15;
    float bv = BIAS ? bias[c] : 0.f;
#pragma unroll
    for (int i = 0; i < 8; ++i) {
      int rbase = bm + wm + i * 16 + quad * 4;
      float4v a = acc[i][j];
#pragma unroll
      for (int reg = 0; reg < 4; ++reg) {
        int r = rbase + reg;
        if (r < M) {
          float v = a[reg] + bv;
          if (RELU) v = fmaxf(v, 0.f);
          if (SCALE) v *= rowscale[r];
          out[(size_t)r * N + c] = (_Float16)v;
        }
      }
    }
  }
}

// ---------------- fp32 tiled GEMM (tail): C = act(A @ B + bias) ----------------

template <int RELU, int BIAS>
__global__ __launch_bounds__(256) void k_gemm(const float* __restrict__ A,
                                              const float* __restrict__ B,
                                              const float* __restrict__ bias,
                                              float* __restrict__ C,
                                              int M, int N, int K) {
  __shared__ float As[16][68];
  __shared__ float Bs[16][68];
  const int bm = blockIdx.y * 64;
  const int bn = blockIdx.x * 64;
  const int tid = threadIdx.x;
  const int tr = (tid >> 4) << 2;
  const int tc = (tid & 15) << 2;
  const int lm  = tid >> 2;
  const int lk  = (tid & 3) << 2;
  const int lk2 = tid >> 4;
  const int ln  = (tid & 15) << 2;
  const bool arow_ok = (bm + lm) < M;
  const float* Aptr = A + (size_t)(bm + lm) * K + lk;
  const float* Bptr = B + (size_t)lk2 * N + bn + ln;
  float acc[4][4] = {};
  for (int k0 = 0; k0 < K; k0 += 16) {
    float4 a4 = make_float4(0.f, 0.f, 0.f, 0.f);
    if (arow_ok) a4 = *(const float4*)(Aptr + k0);
    float4 b4 = *(const float4*)(Bptr + (size_t)k0 * N);
    As[lk + 0][lm] = a4.x;
    As[lk + 1][lm] = a4.y;
    As[lk + 2][lm] = a4.z;
    As[lk + 3][lm] = a4.w;
    *(float4*)&Bs[lk2][ln] = b4;
    __syncthreads();
#pragma unroll
    for (int k = 0; k < 16; ++k) {
      float4 av = *(const float4*)&As[k][tr];
      float4 bv = *(const float4*)&Bs[k][tc];
      float a[4] = {av.x, av.y, av.z, av.w};
      float b[4] = {bv.x, bv.y, bv.z, bv.w};
#pragma unroll
      for (int i = 0; i < 4; ++i)
#pragma unroll
        for (int j = 0; j < 4; ++j) acc[i][j] += a[i] * b[j];
    }
    __syncthreads();
  }
  float bias_v[4] = {0.f, 0.f, 0.f, 0.f};
  if (BIAS) {
    float4 bb = *(const float4*)(bias + bn + tc);
    bias_v[0] = bb.x; bias_v[1] = bb.y; bias_v[2] = bb.z; bias_v[3] = bb.w;
  }
#pragma unroll
  for (int i = 0; i < 4; ++i) {
    int r = bm + tr + i;
    if (r < M) {
      float4 o;
      o.x = acc[i][0] + bias_v[0];
      o.y = acc[i][1] + bias_v[1];
      o.z = acc[i][2] + bias_v[2];
      o.w = acc[i][3] + bias_v[3];
      if (RELU) {
        o.x = fmaxf(o.x, 0.f); o.y = fmaxf(o.y, 0.f);
        o.z = fmaxf(o.z, 0.f); o.w = fmaxf(o.w, 0.f);
      }
      *(float4*)&C[(size_t)r * N + bn + tc] = o;
    }
  }
}

// ---------------- GCN aggregation (gather, one wave/node, 256 feats) ----------------
// t is PRE-SCALED: t'[i] = t[i]*dinv[i].  out[i] = (t'[i] + sum t'[src]) * dinv[i] + b

template <typename OT>
__global__ __launch_bounds__(256) void k_agg(const _Float16* __restrict__ t,
                                             const int* __restrict__ row_ptr,
                                             const int* __restrict__ csr_src,
                                             const float* __restrict__ dinv,
                                             const float* __restrict__ bias,
                                             OT* __restrict__ out, int n_nodes) {
  int w = (int)((blockIdx.x * 256 + threadIdx.x) >> 6);
  int lane = threadIdx.x & 63;
  if (w >= n_nodes) return;
  float di = dinv[w];
  half4v v = *(const half4v*)(t + (size_t)w * 256 + lane * 4);
  float ax = (float)v[0], ay = (float)v[1], az = (float)v[2], aw = (float)v[3];
  int e0 = row_ptr[w], e1 = row_ptr[w + 1];
  int e = e0;
  for (; e + 4 <= e1; e += 4) {
    int s0 = csr_src[e];
    int s1 = csr_src[e + 1];
    int s2 = csr_src[e + 2];
    int s3 = csr_src[e + 3];
    half4v u0 = *(const half4v*)(t + (size_t)s0 * 256 + lane * 4);
    half4v u1 = *(const half4v*)(t + (size_t)s1 * 256 + lane * 4);
    half4v u2 = *(const half4v*)(t + (size_t)s2 * 256 + lane * 4);
    half4v u3 = *(const half4v*)(t + (size_t)s3 * 256 + lane * 4);
    ax += (float)u0[0] + (float)u1[0] + (float)u2[0] + (float)u3[0];
    ay += (float)u0[1] + (float)u1[1] + (float)u2[1] + (float)u3[1];
    az += (float)u0[2] + (float)u1[2] + (float)u2[2] + (float)u3[2];
    aw += (float)u0[3] + (float)u1[3] + (float)u2[3] + (float)u3[3];
  }
  for (; e < e1; ++e) {
    int s = csr_src[e];
    half4v u = *(const half4v*)(t + (size_t)s * 256 + lane * 4);
    ax += (float)u[0]; ay += (float)u[1]; az += (float)u[2]; aw += (float)u[3];
  }
  const float4 b = ((const float4*)bias)[lane];
  if constexpr (std::is_same_v<OT, float>) {
    float4 o;
    o.x = ax * di + b.x; o.y = ay * di + b.y;
    o.z = az * di + b.z; o.w = aw * di + b.w;
    ((float4*)(out + (size_t)w * 256))[lane] = o;
  } else {
    half4v o;
    o[0] = (_Float16)(ax * di + b.x); o[1] = (_Float16)(ay * di + b.y);
    o[2] = (_Float16)(az * di + b.z); o[3] = (_Float16)(aw * di + b.w);
    *(half4v*)(out + (size_t)w * 256 + lane * 4) = o;
  }
}

// ---------------- classifier: out[M,2] = h[M,K] @ Wc[K,2] + bc ----------------

__global__ __launch_bounds__(256) void k_cls(const float* __restrict__ h,
                                             const float* __restrict__ Wc,
                                             const float* __restrict__ bc,
                                             float* __restrict__ out, int M, int K) {
  __shared__ float w[512];
  for (int i = threadIdx.x; i < 2 * K; i += 256) w[i] = Wc[i];
  __syncthreads();
  int i = blockIdx.x * 256 + threadIdx.x;
  if (i >= M) return;
  float a0 = bc[0], a1 = bc[1];
  const float* hr = h + (size_t)i * K;
  for (int k = 0; k < K; ++k) {
    float a = hr[k];
    a0 += a * w[2 * k];
    a1 += a * w[2 * k + 1];
  }
  out[2 * i] = a0;
  out[2 * i + 1] = a1;
}

// ---------------- launch ----------------

extern "C" void kernel_launch(void* const* d_in, const int* in_sizes, int n_in,
                              void* d_out, int out_size, void* d_ws, size_t ws_size,
                              hipStream_t stream) {
  const float* x   = (const float*)d_in[0];
  const int*   ei  = (const int*)d_in[1];
  const float* W1  = (const float*)d_in[2];
  const float* b1  = (const float*)d_in[3];
  const float* Wg1 = (const float*)d_in[4];
  const float* bg1 = (const float*)d_in[5];
  const float* Wg2 = (const float*)d_in[6];
  const float* bg2 = (const float*)d_in[7];
  const float* W2  = (const float*)d_in[8];
  const float* b2  = (const float*)d_in[9];
  const float* Wc  = (const float*)d_in[10];
  const float* bc  = (const float*)d_in[11];
  float* out = (float*)d_out;

  const int hid     = in_sizes[3];            // 256
  const int in_dim  = in_sizes[2] / hid;      // 768
  const int out_dim = in_sizes[9];            // 128
  const int N       = in_sizes[0] / in_dim;   // 50000
  const int E       = in_sizes[1] / 2;        // 800000
  const int Batch   = out_size / 2;           // 1024

  const int* srcI = ei;
  const int* dstI = ei + E;

  char* ws = (char*)d_ws;
  size_t off = 0;
  auto alloc = [&](size_t bytes) -> void* {
    void* p = ws + off;
    off = (off + bytes + 255) & ~(size_t)255;
    return p;
  };
  _Float16* h0h  = (_Float16*)alloc((size_t)N * hid * 2);
  _Float16* t1h  = (_Float16*)alloc((size_t)N * hid * 2);   // pre-scaled by dinv
  _Float16* h1h  = (_Float16*)alloc((size_t)N * hid * 2);
  _Float16* t2h  = (_Float16*)alloc((size_t)N * hid * 2);   // pre-scaled by dinv
  _Float16* W1t  = (_Float16*)alloc((size_t)in_dim * hid * 2);
  _Float16* Wg1t = (_Float16*)alloc((size_t)hid * hid * 2);
  _Float16* Wg2t = (_Float16*)alloc((size_t)hid * hid * 2);
  float* agg2    = (float*)alloc((size_t)Batch * hid * 4);
  float* h3      = (float*)alloc((size_t)Batch * out_dim * 4);
  float* dinv    = (float*)alloc((size_t)N * 4);
  int*   cnt     = (int*)alloc((size_t)N * 4);
  int*   rowp    = (int*)alloc((size_t)(N + 1) * 4);
  int*   bsum    = (int*)alloc((size_t)1024 * 4);
  int*   cursor  = (int*)alloc((size_t)N * 4);
  int*   csrs    = (int*)alloc((size_t)E * 4);
  (void)ws_size; (void)n_in;

  dim3 blk(256);
  const int nb = (N + 1023) / 1024;

  // CSR + norm build
  k_zero_int<<<(N + 255) / 256, blk, 0, stream>>>(cnt, N);
  k_count<<<(E + 255) / 256, blk, 0, stream>>>(dstI, cnt, E);
  k_scan_local<<<nb, 1024, 0, stream>>>(cnt, rowp, bsum, N);
  k_scan_sums<<<1, 1024, 0, stream>>>(bsum, nb);
  k_finalize<<<(N + 255) / 256, blk, 0, stream>>>(rowp, bsum, cnt, cursor, dinv, N, E);
  k_fill<<<(E + 255) / 256, blk, 0, stream>>>(srcI, dstI, cursor, csrs, E);

  // fused weight convert + transpose (fp16)
  {
    int total = in_dim * hid + 2 * hid * hid;
    k_w_convert_all<<<(total + 255) / 256, blk, 0, stream>>>(W1, Wg1, Wg2, W1t, Wg1t, Wg2t, in_dim, hid);
  }

  const int ng = (N + 255) / 256;   // 196 blocks, full-N output tile
  dim3 gblk(512);
  // h0 = relu(x @ W1 + b1)
  k_gemm_mfma<float, 1, 1, 0><<<dim3(ng), gblk, 0, stream>>>(x, W1t, b1, nullptr, h0h, N, hid, in_dim);
  // t1' = (h0 @ Wg1) * dinv[row]
  k_gemm_mfma<_Float16, 0, 0, 1><<<dim3(ng), gblk, 0, stream>>>(h0h, Wg1t, nullptr, dinv, t1h, N, hid, hid);
  // h1 = (t1'[i] + sum t1'[src]) * dinv[i] + bg1   (fp16 out)
  k_agg<_Float16><<<(N + 3) / 4, blk, 0, stream>>>(t1h, rowp, csrs, dinv, bg1, h1h, N);
  // t2' = (h1 @ Wg2) * dinv[row]
  k_gemm_mfma<_Float16, 0, 0, 1><<<dim3(ng), gblk, 0, stream>>>(h1h, Wg2t, nullptr, dinv, t2h, N, hid, hid);
  // conv2 aggregation only for rows [0, Batch)  (fp32 out)
  k_agg<float><<<(Batch + 3) / 4, blk, 0, stream>>>(t2h, rowp, csrs, dinv, bg2, agg2, Batch);
  // h3 = relu(agg2 @ W2 + b2)
  k_gemm<1, 1><<<dim3(out_dim / 64, (Batch + 63) / 64), blk, 0, stream>>>(agg2, W2, b2, h3, Batch, out_dim, hid);
  // logits = h3 @ Wc + bc
  k_cls<<<(Batch + 255) / 256, blk, 0, stream>>>(h3, Wc, bc, out, Batch, out_dim);
}

// Round 6
// 525.772 us; speedup vs baseline: 1.0181x; 1.0181x over previous
//
#include <hip/hip_runtime.h>
#include <hip/hip_bf16.h>
#include <cstdint>
#include <cstddef>
#include <type_traits>

typedef _Float16 half8 __attribute__((ext_vector_type(8)));
typedef _Float16 half4v __attribute__((ext_vector_type(4)));
typedef float float4v __attribute__((ext_vector_type(4)));

// ---------------- CSR build ----------------

__global__ void k_zero2(int* __restrict__ a, int* __restrict__ b, int n) {
  int i = blockIdx.x * blockDim.x + threadIdx.x;
  if (i < n) { a[i] = 0; b[i] = 0; }
}

__global__ void k_count(const int* __restrict__ dst, int* __restrict__ cnt, int E) {
  int e = blockIdx.x * blockDim.x + threadIdx.x;
  if (e < E) atomicAdd(&cnt[dst[e]], 1);
}

// mark S1 = batch nodes + sources of edges into batch (1-hop in-neighborhood).
// Only these rows of t2 are read by agg2, so only these rows need h1/GEMM3.
__global__ void k_mark(const int* __restrict__ src, const int* __restrict__ dst,
                       int* __restrict__ flag, int E, int Batch) {
  int e = blockIdx.x * blockDim.x + threadIdx.x;
  if (e < E && dst[e] < Batch) flag[src[e]] = 1;
  if (e < Batch) flag[e] = 1;
}

// hierarchical exclusive scan: local (per-1024 block) -> sums -> fixup
__global__ __launch_bounds__(1024) void k_scan_local(const int* __restrict__ cnt,
                                                     int* __restrict__ rowp,
                                                     int* __restrict__ bsum, int n) {
  __shared__ int sm[1024];
  int tid = threadIdx.x;
  int i = blockIdx.x * 1024 + tid;
  int v = (i < n) ? cnt[i] : 0;
  sm[tid] = v;
  __syncthreads();
  for (int off = 1; off < 1024; off <<= 1) {
    int t = (tid >= off) ? sm[tid - off] : 0;
    __syncthreads();
    sm[tid] += t;
    __syncthreads();
  }
  if (i < n) rowp[i] = sm[tid] - v;  // exclusive (pre-fixup)
  if (tid == 1023) bsum[blockIdx.x] = sm[1023];
}

__global__ __launch_bounds__(1024) void k_scan_sums(int* __restrict__ bsum, int nb) {
  __shared__ int sm[1024];
  int tid = threadIdx.x;
  int v = (tid < nb) ? bsum[tid] : 0;
  sm[tid] = v;
  __syncthreads();
  for (int off = 1; off < 1024; off <<= 1) {
    int t = (tid >= off) ? sm[tid - off] : 0;
    __syncthreads();
    sm[tid] += t;
    __syncthreads();
  }
  if (tid < nb) bsum[tid] = sm[tid] - v;  // exclusive
}

// fixup + cursor copy + dinv, fused
__global__ void k_finalize(int* __restrict__ rowp, const int* __restrict__ bsum,
                           const int* __restrict__ cnt, int* __restrict__ cursor,
                           float* __restrict__ dinv, int n, int E) {
  int i = blockIdx.x * blockDim.x + threadIdx.x;
  if (i < n) {
    int v = rowp[i] + bsum[i >> 10];
    rowp[i] = v;
    cursor[i] = v;
    dinv[i] = rsqrtf((float)(cnt[i] + 1));  // +1 self loop
  }
  if (i == 0) rowp[n] = E;
}

__global__ void k_fill(const int* __restrict__ src, const int* __restrict__ dst,
                       int* __restrict__ cursor, int* __restrict__ csr_src, int E) {
  int e = blockIdx.x * blockDim.x + threadIdx.x;
  if (e < E) {
    int pos = atomicAdd(&cursor[dst[e]], 1);
    csr_src[pos] = src[e];
  }
}

// compact flagged nodes into list; write count
__global__ void k_emit(const int* __restrict__ flag, const int* __restrict__ fidx,
                       const int* __restrict__ fbsum, int* __restrict__ list,
                       int* __restrict__ s1cnt, int n) {
  int i = blockIdx.x * blockDim.x + threadIdx.x;
  if (i >= n) return;
  int pos = fidx[i] + fbsum[i >> 10];
  if (flag[i]) list[pos] = i;
  if (i == n - 1) s1cnt[0] = pos + flag[i];
}

// ---------------- fused weight convert+transpose (3 matrices in one launch) --------

__global__ void k_w_convert_all(const float* __restrict__ W1, const float* __restrict__ Wg1,
                                const float* __restrict__ Wg2, _Float16* __restrict__ W1t,
                                _Float16* __restrict__ Wg1t, _Float16* __restrict__ Wg2t,
                                int in_dim, int hid) {
  int idx = blockIdx.x * blockDim.x + threadIdx.x;
  int n1 = in_dim * hid;
  int n2 = hid * hid;
  if (idx < n1) {
    int n = idx / in_dim, k = idx - n * in_dim;
    W1t[idx] = (_Float16)W1[(size_t)k * hid + n];
  } else if (idx < n1 + n2) {
    int i2 = idx - n1;
    int n = i2 / hid, k = i2 - n * hid;
    Wg1t[i2] = (_Float16)Wg1[(size_t)k * hid + n];
  } else if (idx < n1 + 2 * n2) {
    int i2 = idx - n1 - n2;
    int n = i2 / hid, k = i2 - n * hid;
    Wg2t[i2] = (_Float16)Wg2[(size_t)k * hid + n];
  }
}

// ---------------- fp16 MFMA GEMM, 256x256 tile, counted-vmcnt 3-buffer pipeline ----
// (structure harness-verified rounds 3/5; GATHER mode added for S1-pruned GEMM3:
// A rows indexed through list, output scatter-written to node rows, rowscale by
// node id. Blocks beyond the runtime row count exit uniformly before any barrier.)

__device__ __forceinline__ void gl_lds16(const void* g, void* l) {
  __builtin_amdgcn_global_load_lds(
      (const __attribute__((address_space(1))) void*)g,
      (__attribute__((address_space(3))) void*)l, 16, 0, 0);
}

#define VMCNT(n) asm volatile("s_waitcnt vmcnt(" #n ")" ::: "memory")

template <int RA>
__device__ __forceinline__ void dma_tile(const char* const (&aS)[RA], const int (&aD)[RA],
                                         const char* const (&bS)[2], const int (&bD)[2],
                                         char* ab, char* bb, size_t advA, size_t advB) {
#pragma unroll
  for (int rr = 0; rr < RA; ++rr) gl_lds16(aS[rr] + advA, ab + aD[rr]);
#pragma unroll
  for (int rr = 0; rr < 2; ++rr) gl_lds16(bS[rr] + advB, bb + bD[rr]);
}

template <typename AT, int RELU, int BIAS, int SCALE, int GATHER>
__global__ __launch_bounds__(512) void k_gemm_mfma(const AT* __restrict__ A,
                                                   const _Float16* __restrict__ Bt,
                                                   const float* __restrict__ bias,
                                                   const float* __restrict__ rowscale,
                                                   _Float16* __restrict__ out,
                                                   int M, int N, int K,
                                                   const int* __restrict__ ridx,
                                                   const int* __restrict__ rcnt) {
  __shared__ alignas(16) AT Asm[3][256 * 32];
  __shared__ alignas(16) _Float16 Bsm[3][256 * 32];
  constexpr bool AF32 = std::is_same_v<AT, float>;
  constexpr int RA = AF32 ? 4 : 2;                   // A DMA rounds (8KB each)
  constexpr int ABUFB = 256 * 32 * (int)sizeof(AT);  // 32KB / 16KB
  constexpr int BBUFB = 256 * 32 * 2;                // 16KB

  const int tid = threadIdx.x;
  const int wv = tid >> 6;          // 0..7
  const int ln = tid & 63;
  const int quad = ln >> 4;
  const int l15 = ln & 15;
  const int wm = (wv >> 2) * 128;   // 0 or 128
  const int wn = (wv & 3) * 64;     // 0,64,128,192

  const int bm = (int)blockIdx.x * 256;

  int Meff = M;
  if constexpr (GATHER) {
    Meff = rcnt[0];
    if (bm >= Meff) return;         // uniform per block, before any barrier
  }

  // ---- per-thread DMA source precompute (dest linear; source pre-permuted) ----
  const char* aSrcB[RA];
  int aDstOff[RA];
#pragma unroll
  for (int rr = 0; rr < RA; ++rr) {
    int q = rr * 8192 + wv * 1024 + ln * 16;  // byte pos in A buf
    int row, colE;                            // colE in elements
    if constexpr (AF32) {
      int h = q >> 14;                        // half-buffer (cols 0-15 | 16-31)
      row = (q >> 6) & 255;
      colE = ((q & 63) >> 2) + (h << 4);
    } else {
      row = q >> 6;
      colE = (q & 63) >> 1;
    }
    int li = bm + row; if (li > Meff - 1) li = Meff - 1;  // clamp; epilogue masks
    int grow;
    if constexpr (GATHER) grow = ridx[li]; else grow = li;
    aSrcB[rr] = (const char*)(A + (size_t)grow * K + colE);
    aDstOff[rr] = rr * 8192 + wv * 1024;      // wave-uniform (lane*16 added by HW)
  }
  const char* bSrcB[2];
  int bDstOff[2];
#pragma unroll
  for (int rr = 0; rr < 2; ++rr) {
    int q = rr * 8192 + wv * 1024 + ln * 16;  // byte pos in B buf
    int row = q >> 6;
    int colH = (q & 63) >> 1;
    bSrcB[rr] = (const char*)(Bt + (size_t)row * K + colH);
    bDstOff[rr] = rr * 8192 + wv * 1024;
  }

  float4v acc[8][4];
#pragma unroll
  for (int i = 0; i < 8; ++i)
#pragma unroll
    for (int j = 0; j < 4; ++j) acc[i][j] = (float4v){0.f, 0.f, 0.f, 0.f};

  const int nk = K >> 5;   // >= 8 always here

  char* const Ab0 = (char*)&Asm[0][0];
  char* const Bb0 = (char*)&Bsm[0][0];

  // prologue: DMA tile 0 -> buf 0, tile 1 -> buf 1 (2*IPT outstanding)
  dma_tile<RA>(aSrcB, aDstOff, bSrcB, bDstOff, Ab0, Bb0, 0, 0);
  dma_tile<RA>(aSrcB, aDstOff, bSrcB, bDstOff, Ab0 + ABUFB, Bb0 + BBUFB,
               (size_t)32 * sizeof(AT), 64);

  int c0 = 0;  // buffer holding tile kt
  for (int kt = 0; kt < nk; ++kt) {
    // wait: tile kt resident (leave tile kt+1's IPT newest in flight)
    if (kt + 1 < nk) {
      if constexpr (AF32) { VMCNT(6); } else { VMCNT(4); }
    } else {
      VMCNT(0);
    }
    __builtin_amdgcn_sched_barrier(0);
    __builtin_amdgcn_s_barrier();       // publish all waves' tile-kt DMA
    __builtin_amdgcn_sched_barrier(0);

    // issue tile kt+2 DMA into the buffer last read at tile kt-1
    if (kt + 2 < nk) {
      int c2 = c0 + 2; if (c2 >= 3) c2 -= 3;
      dma_tile<RA>(aSrcB, aDstOff, bSrcB, bDstOff,
                   Ab0 + (size_t)c2 * ABUFB, Bb0 + (size_t)c2 * BBUFB,
                   (size_t)(kt + 2) * 32 * sizeof(AT), (size_t)(kt + 2) * 64);
      __builtin_amdgcn_sched_barrier(0);  // keep DMA issue ahead of ds_reads
    }

    // compute tile kt from buffer c0
    const AT* Ab = &Asm[c0][0];
    const _Float16* Bb = &Bsm[c0][0];
    half8 bf[4];
#pragma unroll
    for (int j = 0; j < 4; ++j)
      bf[j] = *(const half8*)(Bb + (wn + j * 16 + l15) * 32 + quad * 8);
#pragma unroll
    for (int i = 0; i < 8; ++i) {
      int rowa = wm + i * 16 + l15;
      half8 af;
      if constexpr (AF32) {
        // split-half: cols quad*8..quad*8+7 live in half (quad>>1), sub (quad&1)
        const float* ap = Ab + (quad >> 1) * 4096 + rowa * 16 + (quad & 1) * 8;
        float4v f0 = *(const float4v*)ap;
        float4v f1 = *(const float4v*)(ap + 4);
        af[0] = (_Float16)f0[0]; af[1] = (_Float16)f0[1];
        af[2] = (_Float16)f0[2]; af[3] = (_Float16)f0[3];
        af[4] = (_Float16)f1[0]; af[5] = (_Float16)f1[1];
        af[6] = (_Float16)f1[2]; af[7] = (_Float16)f1[3];
      } else {
        af = *(const half8*)(Ab + rowa * 32 + quad * 8);
      }
#pragma unroll
      for (int j = 0; j < 4; ++j)
        acc[i][j] = __builtin_amdgcn_mfma_f32_16x16x32_f16(af, bf[j], acc[i][j], 0, 0, 0);
    }

    c0 = (c0 == 2) ? 0 : c0 + 1;
  }

  // epilogue: C/D layout col=lane&15, row=quad*4+reg
#pragma unroll
  for (int j = 0; j < 4; ++j) {
    int c = wn + j * 16 + l15;
    float bv = BIAS ? bias[c] : 0.f;
#pragma unroll
    for (int i = 0; i < 8; ++i) {
      int rbase = bm + wm + i * 16 + quad * 4;
      float4v a = acc[i][j];
#pragma unroll
      for (int reg = 0; reg < 4; ++reg) {
        int r = rbase + reg;
        if (r < Meff) {
          int orow;
          if constexpr (GATHER) orow = ridx[r]; else orow = r;
          float v = a[reg] + bv;
          if (RELU) v = fmaxf(v, 0.f);
          if (SCALE) v *= rowscale[orow];
          out[(size_t)orow * N + c] = (_Float16)v;
        }
      }
    }
  }
}

// ---------------- fp32 tiled GEMM (tail): C = act(A @ B + bias) ----------------

template <int RELU, int BIAS>
__global__ __launch_bounds__(256) void k_gemm(const float* __restrict__ A,
                                              const float* __restrict__ B,
                                              const float* __restrict__ bias,
                                              float* __restrict__ C,
                                              int M, int N, int K) {
  __shared__ float As[16][68];
  __shared__ float Bs[16][68];
  const int bm = blockIdx.y * 64;
  const int bn = blockIdx.x * 64;
  const int tid = threadIdx.x;
  const int tr = (tid >> 4) << 2;
  const int tc = (tid & 15) << 2;
  const int lm  = tid >> 2;
  const int lk  = (tid & 3) << 2;
  const int lk2 = tid >> 4;
  const int ln  = (tid & 15) << 2;
  const bool arow_ok = (bm + lm) < M;
  const float* Aptr = A + (size_t)(bm + lm) * K + lk;
  const float* Bptr = B + (size_t)lk2 * N + bn + ln;
  float acc[4][4] = {};
  for (int k0 = 0; k0 < K; k0 += 16) {
    float4 a4 = make_float4(0.f, 0.f, 0.f, 0.f);
    if (arow_ok) a4 = *(const float4*)(Aptr + k0);
    float4 b4 = *(const float4*)(Bptr + (size_t)k0 * N);
    As[lk + 0][lm] = a4.x;
    As[lk + 1][lm] = a4.y;
    As[lk + 2][lm] = a4.z;
    As[lk + 3][lm] = a4.w;
    *(float4*)&Bs[lk2][ln] = b4;
    __syncthreads();
#pragma unroll
    for (int k = 0; k < 16; ++k) {
      float4 av = *(const float4*)&As[k][tr];
      float4 bv = *(const float4*)&Bs[k][tc];
      float a[4] = {av.x, av.y, av.z, av.w};
      float b[4] = {bv.x, bv.y, bv.z, bv.w};
#pragma unroll
      for (int i = 0; i < 4; ++i)
#pragma unroll
        for (int j = 0; j < 4; ++j) acc[i][j] += a[i] * b[j];
    }
    __syncthreads();
  }
  float bias_v[4] = {0.f, 0.f, 0.f, 0.f};
  if (BIAS) {
    float4 bb = *(const float4*)(bias + bn + tc);
    bias_v[0] = bb.x; bias_v[1] = bb.y; bias_v[2] = bb.z; bias_v[3] = bb.w;
  }
#pragma unroll
  for (int i = 0; i < 4; ++i) {
    int r = bm + tr + i;
    if (r < M) {
      float4 o;
      o.x = acc[i][0] + bias_v[0];
      o.y = acc[i][1] + bias_v[1];
      o.z = acc[i][2] + bias_v[2];
      o.w = acc[i][3] + bias_v[3];
      if (RELU) {
        o.x = fmaxf(o.x, 0.f); o.y = fmaxf(o.y, 0.f);
        o.z = fmaxf(o.z, 0.f); o.w = fmaxf(o.w, 0.f);
      }
      *(float4*)&C[(size_t)r * N + bn + tc] = o;
    }
  }
}

// ---------------- GCN aggregation (gather, one wave/node, 256 feats) ----------------
// t is PRE-SCALED: t'[i] = t[i]*dinv[i].  out[i] = (t'[i] + sum t'[src]) * dinv[i] + b

template <typename OT>
__global__ __launch_bounds__(256) void k_agg(const _Float16* __restrict__ t,
                                             const int* __restrict__ row_ptr,
                                             const int* __restrict__ csr_src,
                                             const float* __restrict__ dinv,
                                             const float* __restrict__ bias,
                                             OT* __restrict__ out, int n_nodes) {
  int w = (int)((blockIdx.x * 256 + threadIdx.x) >> 6);
  int lane = threadIdx.x & 63;
  if (w >= n_nodes) return;
  float di = dinv[w];
  half4v v = *(const half4v*)(t + (size_t)w * 256 + lane * 4);
  float ax = (float)v[0], ay = (float)v[1], az = (float)v[2], aw = (float)v[3];
  int e0 = row_ptr[w], e1 = row_ptr[w + 1];
  int e = e0;
  for (; e + 4 <= e1; e += 4) {
    int s0 = csr_src[e];
    int s1 = csr_src[e + 1];
    int s2 = csr_src[e + 2];
    int s3 = csr_src[e + 3];
    half4v u0 = *(const half4v*)(t + (size_t)s0 * 256 + lane * 4);
    half4v u1 = *(const half4v*)(t + (size_t)s1 * 256 + lane * 4);
    half4v u2 = *(const half4v*)(t + (size_t)s2 * 256 + lane * 4);
    half4v u3 = *(const half4v*)(t + (size_t)s3 * 256 + lane * 4);
    ax += (float)u0[0] + (float)u1[0] + (float)u2[0] + (float)u3[0];
    ay += (float)u0[1] + (float)u1[1] + (float)u2[1] + (float)u3[1];
    az += (float)u0[2] + (float)u1[2] + (float)u2[2] + (float)u3[2];
    aw += (float)u0[3] + (float)u1[3] + (float)u2[3] + (float)u3[3];
  }
  for (; e < e1; ++e) {
    int s = csr_src[e];
    half4v u = *(const half4v*)(t + (size_t)s * 256 + lane * 4);
    ax += (float)u[0]; ay += (float)u[1]; az += (float)u[2]; aw += (float)u[3];
  }
  const float4 b = ((const float4*)bias)[lane];
  if constexpr (std::is_same_v<OT, float>) {
    float4 o;
    o.x = ax * di + b.x; o.y = ay * di + b.y;
    o.z = az * di + b.z; o.w = aw * di + b.w;
    ((float4*)(out + (size_t)w * 256))[lane] = o;
  } else {
    half4v o;
    o[0] = (_Float16)(ax * di + b.x); o[1] = (_Float16)(ay * di + b.y);
    o[2] = (_Float16)(az * di + b.z); o[3] = (_Float16)(aw * di + b.w);
    *(half4v*)(out + (size_t)w * 256 + lane * 4) = o;
  }
}

// list-driven variant: only nodes in list[0..s1cnt) are aggregated (S1 pruning).
__global__ __launch_bounds__(256) void k_agg_g(const _Float16* __restrict__ t,
                                               const int* __restrict__ row_ptr,
                                               const int* __restrict__ csr_src,
                                               const float* __restrict__ dinv,
                                               const float* __restrict__ bias,
                                               _Float16* __restrict__ out,
                                               const int* __restrict__ list,
                                               const int* __restrict__ s1cnt) {
  int wi = (int)((blockIdx.x * 256 + threadIdx.x) >> 6);
  int lane = threadIdx.x & 63;
  if (wi >= s1cnt[0]) return;      // per-wave uniform; no barriers in kernel
  int w = list[wi];
  float di = dinv[w];
  half4v v = *(const half4v*)(t + (size_t)w * 256 + lane * 4);
  float ax = (float)v[0], ay = (float)v[1], az = (float)v[2], aw = (float)v[3];
  int e0 = row_ptr[w], e1 = row_ptr[w + 1];
  int e = e0;
  for (; e + 4 <= e1; e += 4) {
    int s0 = csr_src[e];
    int s1 = csr_src[e + 1];
    int s2 = csr_src[e + 2];
    int s3 = csr_src[e + 3];
    half4v u0 = *(const half4v*)(t + (size_t)s0 * 256 + lane * 4);
    half4v u1 = *(const half4v*)(t + (size_t)s1 * 256 + lane * 4);
    half4v u2 = *(const half4v*)(t + (size_t)s2 * 256 + lane * 4);
    half4v u3 = *(const half4v*)(t + (size_t)s3 * 256 + lane * 4);
    ax += (float)u0[0] + (float)u1[0] + (float)u2[0] + (float)u3[0];
    ay += (float)u0[1] + (float)u1[1] + (float)u2[1] + (float)u3[1];
    az += (float)u0[2] + (float)u1[2] + (float)u2[2] + (float)u3[2];
    aw += (float)u0[3] + (float)u1[3] + (float)u2[3] + (float)u3[3];
  }
  for (; e < e1; ++e) {
    int s = csr_src[e];
    half4v u = *(const half4v*)(t + (size_t)s * 256 + lane * 4);
    ax += (float)u[0]; ay += (float)u[1]; az += (float)u[2]; aw += (float)u[3];
  }
  const float4 b = ((const float4*)bias)[lane];
  half4v o;
  o[0] = (_Float16)(ax * di + b.x); o[1] = (_Float16)(ay * di + b.y);
  o[2] = (_Float16)(az * di + b.z); o[3] = (_Float16)(aw * di + b.w);
  *(half4v*)(out + (size_t)w * 256 + lane * 4) = o;
}

// ---------------- classifier: out[M,2] = h[M,K] @ Wc[K,2] + bc ----------------

__global__ __launch_bounds__(256) void k_cls(const float* __restrict__ h,
                                             const float* __restrict__ Wc,
                                             const float* __restrict__ bc,
                                             float* __restrict__ out, int M, int K) {
  __shared__ float w[512];
  for (int i = threadIdx.x; i < 2 * K; i += 256) w[i] = Wc[i];
  __syncthreads();
  int i = blockIdx.x * 256 + threadIdx.x;
  if (i >= M) return;
  float a0 = bc[0], a1 = bc[1];
  const float* hr = h + (size_t)i * K;
  for (int k = 0; k < K; ++k) {
    float a = hr[k];
    a0 += a * w[2 * k];
    a1 += a * w[2 * k + 1];
  }
  out[2 * i] = a0;
  out[2 * i + 1] = a1;
}

// ---------------- launch ----------------

extern "C" void kernel_launch(void* const* d_in, const int* in_sizes, int n_in,
                              void* d_out, int out_size, void* d_ws, size_t ws_size,
                              hipStream_t stream) {
  const float* x   = (const float*)d_in[0];
  const int*   ei  = (const int*)d_in[1];
  const float* W1  = (const float*)d_in[2];
  const float* b1  = (const float*)d_in[3];
  const float* Wg1 = (const float*)d_in[4];
  const float* bg1 = (const float*)d_in[5];
  const float* Wg2 = (const float*)d_in[6];
  const float* bg2 = (const float*)d_in[7];
  const float* W2  = (const float*)d_in[8];
  const float* b2  = (const float*)d_in[9];
  const float* Wc  = (const float*)d_in[10];
  const float* bc  = (const float*)d_in[11];
  float* out = (float*)d_out;

  const int hid     = in_sizes[3];            // 256
  const int in_dim  = in_sizes[2] / hid;      // 768
  const int out_dim = in_sizes[9];            // 128
  const int N       = in_sizes[0] / in_dim;   // 50000
  const int E       = in_sizes[1] / 2;        // 800000
  const int Batch   = out_size / 2;           // 1024

  const int* srcI = ei;
  const int* dstI = ei + E;

  char* ws = (char*)d_ws;
  size_t off = 0;
  auto alloc = [&](size_t bytes) -> void* {
    void* p = ws + off;
    off = (off + bytes + 255) & ~(size_t)255;
    return p;
  };
  _Float16* h0h  = (_Float16*)alloc((size_t)N * hid * 2);
  _Float16* t1h  = (_Float16*)alloc((size_t)N * hid * 2);   // pre-scaled by dinv
  _Float16* h1h  = (_Float16*)alloc((size_t)N * hid * 2);   // only S1 rows valid
  _Float16* t2h  = (_Float16*)alloc((size_t)N * hid * 2);   // only S1 rows valid
  _Float16* W1t  = (_Float16*)alloc((size_t)in_dim * hid * 2);
  _Float16* Wg1t = (_Float16*)alloc((size_t)hid * hid * 2);
  _Float16* Wg2t = (_Float16*)alloc((size_t)hid * hid * 2);
  float* agg2    = (float*)alloc((size_t)Batch * hid * 4);
  float* h3      = (float*)alloc((size_t)Batch * out_dim * 4);
  float* dinv    = (float*)alloc((size_t)N * 4);
  int*   cnt     = (int*)alloc((size_t)N * 4);
  int*   rowp    = (int*)alloc((size_t)(N + 1) * 4);
  int*   bsum    = (int*)alloc((size_t)1024 * 4);
  int*   cursor  = (int*)alloc((size_t)N * 4);
  int*   csrs    = (int*)alloc((size_t)E * 4);
  int*   flag    = (int*)alloc((size_t)N * 4);
  int*   fidx    = (int*)alloc((size_t)N * 4);
  int*   list    = (int*)alloc((size_t)N * 4);
  int*   s1cnt   = (int*)alloc((size_t)64);
  (void)ws_size; (void)n_in;

  dim3 blk(256);
  const int nb = (N + 1023) / 1024;

  // CSR + norm build
  k_zero2<<<(N + 255) / 256, blk, 0, stream>>>(cnt, flag, N);
  k_count<<<(E + 255) / 256, blk, 0, stream>>>(dstI, cnt, E);
  k_mark<<<(E + 255) / 256, blk, 0, stream>>>(srcI, dstI, flag, E, Batch);
  k_scan_local<<<nb, 1024, 0, stream>>>(cnt, rowp, bsum, N);
  k_scan_sums<<<1, 1024, 0, stream>>>(bsum, nb);
  k_finalize<<<(N + 255) / 256, blk, 0, stream>>>(rowp, bsum, cnt, cursor, dinv, N, E);
  k_fill<<<(E + 255) / 256, blk, 0, stream>>>(srcI, dstI, cursor, csrs, E);
  // S1 compaction (bsum reusable after k_finalize)
  k_scan_local<<<nb, 1024, 0, stream>>>(flag, fidx, bsum, N);
  k_scan_sums<<<1, 1024, 0, stream>>>(bsum, nb);
  k_emit<<<(N + 255) / 256, blk, 0, stream>>>(flag, fidx, bsum, list, s1cnt, N);

  // fused weight convert + transpose (fp16)
  {
    int total = in_dim * hid + 2 * hid * hid;
    k_w_convert_all<<<(total + 255) / 256, blk, 0, stream>>>(W1, Wg1, Wg2, W1t, Wg1t, Wg2t, in_dim, hid);
  }

  const int ng = (N + 255) / 256;   // 196 blocks, full-N output tile
  dim3 gblk(512);
  // h0 = relu(x @ W1 + b1)
  k_gemm_mfma<float, 1, 1, 0, 0><<<dim3(ng), gblk, 0, stream>>>(x, W1t, b1, nullptr, h0h, N, hid, in_dim, nullptr, nullptr);
  // t1' = (h0 @ Wg1) * dinv[row]   (all nodes: t1[src] needed for arbitrary src)
  k_gemm_mfma<_Float16, 0, 0, 1, 0><<<dim3(ng), gblk, 0, stream>>>(h0h, Wg1t, nullptr, dinv, t1h, N, hid, hid, nullptr, nullptr);
  // h1 = (t1'[i] + sum t1'[src]) * dinv[i] + bg1   -- S1 nodes only
  k_agg_g<<<(N + 3) / 4, blk, 0, stream>>>(t1h, rowp, csrs, dinv, bg1, h1h, list, s1cnt);
  // t2' = (h1 @ Wg2) * dinv[row]   -- gather over S1 rows, scatter to node rows
  k_gemm_mfma<_Float16, 0, 0, 1, 1><<<dim3(ng), gblk, 0, stream>>>(h1h, Wg2t, nullptr, dinv, t2h, N, hid, hid, list, s1cnt);
  // conv2 aggregation only for rows [0, Batch)  (fp32 out)
  k_agg<float><<<(Batch + 3) / 4, blk, 0, stream>>>(t2h, rowp, csrs, dinv, bg2, agg2, Batch);
  // h3 = relu(agg2 @ W2 + b2)
  k_gemm<1, 1><<<dim3(out_dim / 64, (Batch + 63) / 64), blk, 0, stream>>>(agg2, W2, b2, h3, Batch, out_dim, hid);
  // logits = h3 @ Wc + bc
  k_cls<<<(Batch + 255) / 256, blk, 0, stream>>>(h3, Wc, bc, out, Batch, out_dim);
}